// Round 10
// baseline (125.340 us; speedup 1.0000x reference)
//
#include <hip/hip_runtime.h>
#include <math.h>
#include <stdint.h>

#define N 4096
#define Dm 1024
#define BM 128
#define BN 128
#define BK 64
#define NCB (N / 64)   // 64 column-partials per row
#define NPART 512      // combine blocks -> scalar partials

typedef __attribute__((ext_vector_type(8))) short bf16x8;
typedef __attribute__((ext_vector_type(4))) float f32x4;

typedef const void __attribute__((address_space(1)))* gas_t;
typedef void __attribute__((address_space(3)))* las_t;

static __device__ __forceinline__ void gload_lds16(const void* g, void* l) {
    // async global->LDS, 16B per lane; LDS dest is wave-uniform base + lane*16
    __builtin_amdgcn_global_load_lds((gas_t)g, (las_t)l, 16, 0, 0);
}

static __device__ __forceinline__ unsigned short f2bf(float f) {
    unsigned int u = __float_as_uint(f);
    unsigned int r = (u + 0x7fff + ((u >> 16) & 1)) >> 16;  // RNE
    return (unsigned short)r;
}

// Kernel 1: convert A,P -> bf16 + per-row diag dot + L2 partial. One wave per row.
__global__ __launch_bounds__(256) void prep_kernel(const float* __restrict__ A,
                                                   const float* __restrict__ P,
                                                   unsigned short* __restrict__ Abf,
                                                   unsigned short* __restrict__ Pbf,
                                                   float* __restrict__ D,
                                                   float* __restrict__ rowl2) {
    int t = threadIdx.x;
    int lane = t & 63;
    int row = blockIdx.x * 4 + (t >> 6);
    const float4* a4 = (const float4*)(A + (size_t)row * Dm);
    const float4* p4 = (const float4*)(P + (size_t)row * Dm);
    ushort4* ao = (ushort4*)(Abf + (size_t)row * Dm);
    ushort4* po = (ushort4*)(Pbf + (size_t)row * Dm);
    float dot = 0.0f, l2 = 0.0f;
#pragma unroll
    for (int c = 0; c < 4; ++c) {
        int idx = c * 64 + lane;              // coalesced within the wave
        float4 a = a4[idx], p = p4[idx];
        ushort4 ab, pb;
        ab.x = f2bf(a.x); ab.y = f2bf(a.y); ab.z = f2bf(a.z); ab.w = f2bf(a.w);
        pb.x = f2bf(p.x); pb.y = f2bf(p.y); pb.z = f2bf(p.z); pb.w = f2bf(p.w);
        ao[idx] = ab; po[idx] = pb;
        dot += a.x * p.x + a.y * p.y + a.z * p.z + a.w * p.w;
        l2  += a.x * a.x + a.y * a.y + a.z * a.z + a.w * a.w
             + p.x * p.x + p.y * p.y + p.z * p.z + p.w * p.w;
    }
#pragma unroll
    for (int off = 32; off; off >>= 1) {
        dot += __shfl_xor(dot, off, 64);
        l2  += __shfl_xor(l2,  off, 64);
    }
    if (lane == 0) {
        D[row]     = dot;
        rowl2[row] = l2;
    }
}

// Kernel 2 (plateau K-loop, frozen — R4..R9 + m99-m141 establish it): bf16 MFMA GEMM,
// 128x128 tile, BK=64, XOR-swizzled conflict-free LDS, global_load_lds(16B) staging,
// fused flash-style epilogue. NEW in R10: per-XCD 8x8 block patches (A 2MB + B 2MB =
// 4MB = exactly one XCD's L2, matching the ~48-blocks/XCD concurrency footprint),
// serpentine-ordered. Pure relabeling of block IDs.
__global__ __launch_bounds__(256) void npair_mfma(const unsigned short* __restrict__ Abf,
                                                  const unsigned short* __restrict__ Pbf,
                                                  const float* __restrict__ D,
                                                  float* __restrict__ Mpart,
                                                  float* __restrict__ Spart) {
    __shared__ unsigned short At[BM * BK];   // 16 KB, row stride 128 B = 32 banks
    __shared__ unsigned short Bt[BN * BK];   // 16 KB
    __shared__ float Ds[BM];
    int tid = threadIdx.x;
    int wid = tid >> 6, lane = tid & 63;
    int wr = wid >> 1, wc = wid & 1;         // 2x2 waves, each owns 64x64 output

    // XCD-aware swizzle v2: 1024 blocks -> 8 XCDs round-robin; each XCD owns two 8x8
    // patches of the 32x32 tile grid ({xcd, xcd+8} in a 4x4 patch grid), serpentine
    // within the patch. Concurrent working set per XCD = 8 A-tiles + 8 B-tiles = 4 MB.
    int bid = blockIdx.y * gridDim.x + blockIdx.x;
    int xcd = bid & 7, lid = bid >> 3;       // lid in [0,128)
    int pidx = xcd + ((lid >> 6) << 3);      // patch index 0..15
    int prow = pidx >> 2, pcol = pidx & 3;   // 4x4 patch grid
    int pl = lid & 63;                       // position within 8x8 patch
    int sy = pl >> 3, sx = pl & 7;
    sx = (sy & 1) ? (7 - sx) : sx;           // serpentine for temporal locality
    int by = prow * 8 + sy;                  // [0,32)
    int bx = pcol * 8 + sx;                  // [0,32)
    int row0 = by * BM, col0 = bx * BN;

    // Loader: 1024 slots of 16B per tile; slot L = row*8 + c holds global k-chunk
    // (c^(row&7)). Swizzle applied in the GLOBAL fetch address; LDS dest lane-ordered.
    const unsigned short* gA[4]; const unsigned short* gB[4];
    unsigned short* lA[4]; unsigned short* lB[4];
#pragma unroll
    for (int b = 0; b < 4; ++b) {
        int L = b * 256 + tid;
        int row = L >> 3, c = L & 7;
        int kch = c ^ (row & 7);
        gA[b] = Abf + (size_t)(row0 + row) * Dm + (kch << 3);
        gB[b] = Pbf + (size_t)(col0 + row) * Dm + (kch << 3);
        lA[b] = At + (size_t)L * 8;
        lB[b] = Bt + (size_t)L * 8;
    }
    if (tid < BM) Ds[tid] = D[row0 + tid];

    f32x4 acc[4][4] = {};

    for (int kt = 0; kt < Dm; kt += BK) {    // 16 iterations
        __syncthreads();                      // prior frag reads done before overwrite
#pragma unroll
        for (int b = 0; b < 4; ++b) {
            gload_lds16(gA[b] + kt, lA[b]);
            gload_lds16(gB[b] + kt, lB[b]);
        }
        __syncthreads();                      // drains vmcnt(0): LDS tiles ready
#pragma unroll
        for (int ks = 0; ks < 2; ++ks) {
            bf16x8 af[4], bfr[4];
#pragma unroll
            for (int i = 0; i < 4; ++i) {
                int g = (ks << 2) + (lane >> 4);          // global chunk 0..7 in this row
                int arow = wr * 64 + i * 16 + (lane & 15);
                af[i]  = *(const bf16x8*)(At + arow * BK + ((g ^ (arow & 7)) << 3));
                int brow = wc * 64 + i * 16 + (lane & 15);
                bfr[i] = *(const bf16x8*)(Bt + brow * BK + ((g ^ (brow & 7)) << 3));
            }
#pragma unroll
            for (int i = 0; i < 4; ++i)
#pragma unroll
                for (int j = 0; j < 4; ++j)
                    acc[i][j] = __builtin_amdgcn_mfma_f32_16x16x32_bf16(af[i], bfr[j], acc[i][j], 0, 0, 0);
        }
    }

    // Epilogue. C/D layout: col = lane&15, row = (lane>>4)*4 + reg  [m89/m91 verified]
    int cb = bx * 2 + wc;                    // column-partial slot, NCB=64 per row
#pragma unroll
    for (int rt = 0; rt < 4; ++rt) {
        int rloc = wr * 64 + rt * 16 + ((lane >> 4) << 2);
#pragma unroll
        for (int e = 0; e < 4; ++e) {
            int gr = row0 + rloc + e;
            float Dv = Ds[rloc + e];
            float xs[4];
            float m = -INFINITY;
#pragma unroll
            for (int ct = 0; ct < 4; ++ct) {
                int gc = col0 + wc * 64 + ct * 16 + (lane & 15);
                float x = acc[rt][ct][e] - Dv;
                if (gr == gc) x = -INFINITY;  // mask diagonal
                xs[ct] = x;
                m = fmaxf(m, x);
            }
#pragma unroll
            for (int off = 8; off; off >>= 1) m = fmaxf(m, __shfl_xor(m, off, 64));
            float s = 0.0f;
#pragma unroll
            for (int ct = 0; ct < 4; ++ct) s += __expf(xs[ct] - m);  // exp(-inf)=0 on diag
#pragma unroll
            for (int off = 8; off; off >>= 1) s += __shfl_xor(s, off, 64);
            if ((lane & 15) == 0) {
                Mpart[(size_t)gr * NCB + cb] = m;
                Spart[(size_t)gr * NCB + cb] = s;
            }
        }
    }
}

// Kernel 3: per-row logsumexp combine; each block (8 rows) emits ONE partial pair.
__global__ __launch_bounds__(256) void combine_rows(const float* __restrict__ Mpart,
                                                    const float* __restrict__ Spart,
                                                    const float* __restrict__ rowl2,
                                                    float* __restrict__ partL,
                                                    float* __restrict__ partR) {
    int t = threadIdx.x;
    int lane = t & 63;
    int w = t >> 6;
    __shared__ float ls[8];
#pragma unroll
    for (int r = 0; r < 2; ++r) {
        int row = blockIdx.x * 8 + w * 2 + r;
        float mp = Mpart[(size_t)row * NCB + lane];
        float sp = Spart[(size_t)row * NCB + lane];
        float m = mp;
#pragma unroll
        for (int off = 32; off; off >>= 1) m = fmaxf(m, __shfl_xor(m, off, 64));
        float s = sp * __expf(mp - m);
#pragma unroll
        for (int off = 32; off; off >>= 1) s += __shfl_xor(s, off, 64);
        if (lane == 0) ls[w * 2 + r] = m + logf(__expf(-m) + s);  // log1p(sum exp), safe
    }
    __syncthreads();
    if (t == 0) {
        int r8 = blockIdx.x * 8;
        float L = 0.0f, R = 0.0f;
#pragma unroll
        for (int r = 0; r < 8; ++r) { L += ls[r]; R += rowl2[r8 + r]; }
        partL[blockIdx.x] = L;
        partR[blockIdx.x] = R;
    }
}

// Kernel 4: final scalar from 512 partial pairs.
__global__ __launch_bounds__(256) void final_reduce(const float* __restrict__ partL,
                                                    const float* __restrict__ partR,
                                                    float* __restrict__ out) {
    int t = threadIdx.x;
    float accL = partL[t] + partL[t + 256];
    float acc2 = partR[t] + partR[t + 256];
#pragma unroll
    for (int off = 32; off; off >>= 1) {
        accL += __shfl_xor(accL, off, 64);
        acc2 += __shfl_xor(acc2, off, 64);
    }
    __shared__ float sa[4], sb[4];
    int wave = t >> 6;
    if ((t & 63) == 0) { sa[wave] = accL; sb[wave] = acc2; }
    __syncthreads();
    if (t == 0) {
        float L  = sa[0] + sa[1] + sa[2] + sa[3];
        float l2 = sb[0] + sb[1] + sb[2] + sb[3];
        out[0] = L / (float)N + 0.02f * (l2 / (float)N);
    }
}

extern "C" void kernel_launch(void* const* d_in, const int* in_sizes, int n_in,
                              void* d_out, int out_size, void* d_ws, size_t ws_size,
                              hipStream_t stream) {
    const float* A = (const float*)d_in[0];
    const float* P = (const float*)d_in[1];
    float* out = (float*)d_out;

    unsigned short* Abf = (unsigned short*)d_ws;            // N*Dm bf16 = 8 MiB
    unsigned short* Pbf = Abf + (size_t)N * Dm;             // 8 MiB
    float* D     = (float*)(Pbf + (size_t)N * Dm);          // N
    float* rowl2 = D + N;                                   // N
    float* partL = rowl2 + N;                               // NPART
    float* partR = partL + NPART;                           // NPART
    float* Mpart = partR + NPART;                           // N*NCB = 1 MiB
    float* Spart = Mpart + (size_t)N * NCB;                 // 1 MiB

    prep_kernel<<<N / 4, 256, 0, stream>>>(A, P, Abf, Pbf, D, rowl2);
    dim3 grid(N / BN, N / BM);
    npair_mfma<<<grid, 256, 0, stream>>>(Abf, Pbf, D, Mpart, Spart);
    combine_rows<<<N / 8, 256, 0, stream>>>(Mpart, Spart, rowl2, partL, partR);
    final_reduce<<<1, 256, 0, stream>>>(partL, partR, out);
}